// Round 1
// baseline (208.765 us; speedup 1.0000x reference)
//
#include <hip/hip_runtime.h>
#include <stdint.h>

#define B_  2048
#define D_  1024
#define F_  1024
#define S_  64
#define R_  16

typedef __attribute__((ext_vector_type(8))) short  s16x8;
typedef __attribute__((ext_vector_type(4))) unsigned short u16x4;
typedef __attribute__((ext_vector_type(8))) unsigned short u16x8;
typedef __attribute__((ext_vector_type(4))) float  f32x4;

__device__ __forceinline__ unsigned short f2b(float f){
  unsigned u = __float_as_uint(f);
  u = u + 0x7fffu + ((u >> 16) & 1u);   // RNE to bf16
  return (unsigned short)(u >> 16);
}
__device__ __forceinline__ float b2f(unsigned short s){
  return __uint_as_float(((unsigned)s) << 16);
}

__device__ __forceinline__ void gload16(const void* g, void* l){
  __builtin_amdgcn_global_load_lds((const __attribute__((address_space(1))) unsigned int*)g,
                                   (__attribute__((address_space(3))) unsigned int*)l, 16, 0, 0);
}

// ---------------- kernel 1a: XC = [bf16(x) | bf16(carry)]  (B x 2048) ----------------
__global__ void cast_xc_kernel(const float* __restrict__ x, const float* __restrict__ carry,
                               unsigned short* __restrict__ XC){
  int i = blockIdx.x * blockDim.x + threadIdx.x;   // one float4 per row-half
  if (i >= B_ * (D_/4)) return;
  int b = i >> 8;
  int j = (i & 255) * 4;
  float4 xv = *(const float4*)&x[(size_t)b*D_ + j];
  float4 cv = *(const float4*)&carry[(size_t)b*F_ + j];
  u16x4 xs, cs;
  xs[0]=f2b(xv.x); xs[1]=f2b(xv.y); xs[2]=f2b(xv.z); xs[3]=f2b(xv.w);
  cs[0]=f2b(cv.x); cs[1]=f2b(cv.y); cs[2]=f2b(cv.z); cs[3]=f2b(cv.w);
  *(u16x4*)&XC[(size_t)b*2048 + j]        = xs;
  *(u16x4*)&XC[(size_t)b*2048 + 1024 + j] = cs;
}

// ---------------- kernel 1b: transpose-cast weights into Wt[n][k] bf16 ----------------
__global__ void wcast_kernel(const float* __restrict__ w_ir, const float* __restrict__ w_iu,
                             const float* __restrict__ w_ic, const float* __restrict__ w_rr,
                             const float* __restrict__ w_ru, const float* __restrict__ w_rc,
                             unsigned short* __restrict__ W0t, unsigned short* __restrict__ W1t,
                             unsigned short* __restrict__ W2t, unsigned short* __restrict__ W3t){
  int g = blockIdx.y;
  const float* W; unsigned short* O; int st, ko;
  switch(g){
    case 0:  W=w_ir; O=W0t; st=2048; ko=0;    break;
    case 1:  W=w_iu; O=W1t; st=2048; ko=0;    break;
    case 2:  W=w_ic; O=W2t; st=1024; ko=0;    break;
    case 3:  W=w_rr; O=W0t; st=2048; ko=1024; break;
    case 4:  W=w_ru; O=W1t; st=2048; ko=1024; break;
    default: W=w_rc; O=W3t; st=1024; ko=0;    break;
  }
  __shared__ unsigned short T[64][72];   // row stride 144B = 9*16B (aligned)
  int t = threadIdx.x;
  int n0 = (blockIdx.x & 15) * 64;
  int k0 = (blockIdx.x >> 4) * 64;
  int c4 = (t & 15) * 4;
  int kk = t >> 4;
  #pragma unroll
  for (int i = 0; i < 4; i++){
    int k = kk + i*16;
    float4 v = *(const float4*)&W[(size_t)(k0+k)*F_ + n0 + c4];
    T[c4+0][k] = f2b(v.x); T[c4+1][k] = f2b(v.y); T[c4+2][k] = f2b(v.z); T[c4+3][k] = f2b(v.w);
  }
  __syncthreads();
  int n = t >> 2, ch = (t & 3) * 16;
  u16x8 a = *(const u16x8*)&T[n][ch];
  u16x8 b = *(const u16x8*)&T[n][ch+8];
  *(u16x8*)&O[(size_t)(n0+n)*st + ko + k0 + ch]     = a;
  *(u16x8*)&O[(size_t)(n0+n)*st + ko + k0 + ch + 8] = b;
}

// ---------------- kernel 2: bucket examples by adapter id ----------------
__global__ void bucket_kernel(const int* __restrict__ ids, int* __restrict__ starts,
                              int* __restrict__ order){
  __shared__ int cnt[S_]; __shared__ int off[S_+1]; __shared__ int cur[S_];
  int t = threadIdx.x;
  if (t < S_) cnt[t] = 0;
  __syncthreads();
  for (int b = t; b < B_; b += 256) atomicAdd(&cnt[ids[b]], 1);
  __syncthreads();
  if (t == 0){ off[0] = 0; for (int s2 = 0; s2 < S_; s2++) off[s2+1] = off[s2] + cnt[s2]; }
  __syncthreads();
  if (t < S_) cur[t] = off[t];
  __syncthreads();
  for (int b = t; b < B_; b += 256){ int p = atomicAdd(&cur[ids[b]], 1); order[p] = b; }
  if (t < S_+1) starts[t] = off[t];
}

// ---------------- kernel 3: low[g][b][r] = src[b,:] . la_g[id[b]][:,r] ----------------
__global__ void low_kernel(const float* __restrict__ x, const float* __restrict__ carry,
                           const float* __restrict__ la_ir, const float* __restrict__ la_iu,
                           const float* __restrict__ la_ic, const float* __restrict__ la_rr,
                           const float* __restrict__ la_ru, const float* __restrict__ la_rc,
                           const int* __restrict__ starts, const int* __restrict__ order,
                           float* __restrict__ low){
  int s = blockIdx.x, g = blockIdx.y;
  const float* la;
  switch(g){ case 0: la=la_ir; break; case 1: la=la_iu; break; case 2: la=la_ic; break;
             case 3: la=la_rr; break; case 4: la=la_ru; break; default: la=la_rc; break; }
  const float* src = (g < 3) ? x : carry;
  la += (size_t)s * D_ * R_;
  __shared__ unsigned short A[D_ * R_];   // 32 KB, [d][r] bf16
  int t = threadIdx.x;
  for (int i4 = t; i4 < D_*R_/4; i4 += 256){
    float4 v = *(const float4*)&la[i4*4];
    u16x4 o; o[0]=f2b(v.x); o[1]=f2b(v.y); o[2]=f2b(v.z); o[3]=f2b(v.w);
    *(u16x4*)&A[i4*4] = o;
  }
  __syncthreads();
  int start = starts[s], cnt = starts[s+1] - start;
  int r = t & 15, mi = t >> 4;
  for (int m = mi; m < cnt; m += 16){
    int b = order[start + m];
    const float* xr = &src[(size_t)b * D_];
    float acc = 0.f;
    for (int d = 0; d < D_; d += 4){
      float4 xv = *(const float4*)&xr[d];
      acc += xv.x * b2f(A[(d+0)*R_ + r]);
      acc += xv.y * b2f(A[(d+1)*R_ + r]);
      acc += xv.z * b2f(A[(d+2)*R_ + r]);
      acc += xv.w * b2f(A[(d+3)*R_ + r]);
    }
    low[((size_t)g * B_ + b) * R_ + r] = acc;
  }
}

// ---------------- kernel 4: MFMA GEMM: Yz = A(XC slice) @ Wzt^T ----------------
__global__ __launch_bounds__(256, 2) void gemm_kernel(
    const unsigned short* __restrict__ XC,
    const unsigned short* __restrict__ W0t, const unsigned short* __restrict__ W1t,
    const unsigned short* __restrict__ W2t, const unsigned short* __restrict__ W3t,
    float* __restrict__ Y0, float* __restrict__ Y1,
    float* __restrict__ Y2, float* __restrict__ Y3){
  int z = blockIdx.y;
  const unsigned short* Wt; float* Y; int K, kofs;
  if (z == 0){ Wt = W0t; Y = Y0; K = 2048; kofs = 0; }
  else if (z == 1){ Wt = W1t; Y = Y1; K = 2048; kofs = 0; }
  else if (z == 2){ Wt = W2t; Y = Y2; K = 1024; kofs = 0; }
  else { Wt = W3t; Y = Y3; K = 1024; kofs = 1024; }

  __shared__ unsigned short As[128*32];  // [128 rows][32 k] bf16
  __shared__ unsigned short Ws[128*32];  // [128 cols][32 k] bf16

  int t = threadIdx.x;
  int lane = t & 63, wave = t >> 6;
  int mt = blockIdx.x >> 3, nt = blockIdx.x & 7;
  int row0 = mt * 128, col0 = nt * 128;
  int wrow = (wave >> 1) * 64, wcol = (wave & 1) * 64;

  int arow = t >> 2;          // 0..63
  int achk = (t & 3) * 8;     // k element offset (8 bf16 = 16B)

  f32x4 acc[4][4] = {};

  const unsigned short* Abase  = XC + (size_t)(row0 + arow) * 2048 + kofs + achk;
  const unsigned short* A2base = Abase + (size_t)64 * 2048;
  const unsigned short* Wbase  = Wt + (size_t)(col0 + arow) * K + achk;
  const unsigned short* W2base = Wbase + (size_t)64 * K;

  int l15 = lane & 15, kof = (lane >> 4) * 8;

  for (int kt = 0; kt < K; kt += 32){
    gload16(Abase  + kt, &As[t*8]);
    gload16(A2base + kt, &As[2048 + t*8]);
    gload16(Wbase  + kt, &Ws[t*8]);
    gload16(W2base + kt, &Ws[2048 + t*8]);
    __syncthreads();
    s16x8 af[4], bfr[4];
    #pragma unroll
    for (int m = 0; m < 4; m++)
      af[m] = *(const s16x8*)&As[(wrow + m*16 + l15)*32 + kof];
    #pragma unroll
    for (int n = 0; n < 4; n++)
      bfr[n] = *(const s16x8*)&Ws[(wcol + n*16 + l15)*32 + kof];
    #pragma unroll
    for (int m = 0; m < 4; m++){
      #pragma unroll
      for (int n = 0; n < 4; n++){
        acc[m][n] = __builtin_amdgcn_mfma_f32_16x16x32_bf16(af[m], bfr[n], acc[m][n], 0, 0, 0);
      }
    }
    __syncthreads();
  }

  int orow = row0 + wrow + (lane >> 4) * 4;
  int ocol = col0 + wcol + l15;
  #pragma unroll
  for (int m = 0; m < 4; m++){
    #pragma unroll
    for (int n = 0; n < 4; n++){
      #pragma unroll
      for (int i = 0; i < 4; i++){
        Y[(size_t)(orow + m*16 + i) * F_ + ocol + n*16] = acc[m][n][i];
      }
    }
  }
}

// ---------------- kernel 5: Yz += low_gA @ lb_gA[id]  (+ low_gB @ lb_gB[id]) ----------------
__global__ void delta_kernel(const float* __restrict__ lb_ir, const float* __restrict__ lb_iu,
                             const float* __restrict__ lb_ic, const float* __restrict__ lb_rr,
                             const float* __restrict__ lb_ru, const float* __restrict__ lb_rc,
                             const int* __restrict__ starts, const int* __restrict__ order,
                             const float* __restrict__ low,
                             float* __restrict__ Y0, float* __restrict__ Y1,
                             float* __restrict__ Y2, float* __restrict__ Y3){
  int s = blockIdx.x, z = blockIdx.y;
  const float* lbs[6] = {lb_ir, lb_iu, lb_ic, lb_rr, lb_ru, lb_rc};
  int gA, gB; float* Y;
  if (z == 0){ gA = 0; gB = 3; Y = Y0; }
  else if (z == 1){ gA = 1; gB = 4; Y = Y1; }
  else if (z == 2){ gA = 2; gB = -1; Y = Y2; }
  else { gA = 5; gB = -1; Y = Y3; }

  __shared__ unsigned short LA[R_*F_];   // 32 KB
  __shared__ unsigned short LB[R_*F_];   // 32 KB
  int t = threadIdx.x;
  const float* lbA = lbs[gA] + (size_t)s * R_ * F_;
  for (int i4 = t; i4 < R_*F_/4; i4 += 256){
    float4 v = *(const float4*)&lbA[i4*4];
    u16x4 o; o[0]=f2b(v.x); o[1]=f2b(v.y); o[2]=f2b(v.z); o[3]=f2b(v.w);
    *(u16x4*)&LA[i4*4] = o;
  }
  if (gB >= 0){
    const float* lbB = lbs[gB] + (size_t)s * R_ * F_;
    for (int i4 = t; i4 < R_*F_/4; i4 += 256){
      float4 v = *(const float4*)&lbB[i4*4];
      u16x4 o; o[0]=f2b(v.x); o[1]=f2b(v.y); o[2]=f2b(v.z); o[3]=f2b(v.w);
      *(u16x4*)&LB[i4*4] = o;
    }
  }
  __syncthreads();
  int start = starts[s], cnt = starts[s+1] - start;
  for (int m = 0; m < cnt; m++){
    int b = order[start + m];
    float4 v = *(float4*)&Y[(size_t)b * F_ + t*4];
    const float* lwA = &low[((size_t)gA * B_ + b) * R_];
    #pragma unroll
    for (int r = 0; r < R_; r++){
      float lv = lwA[r];
      u16x4 w = *(const u16x4*)&LA[r*F_ + t*4];
      v.x += lv * b2f(w[0]); v.y += lv * b2f(w[1]);
      v.z += lv * b2f(w[2]); v.w += lv * b2f(w[3]);
    }
    if (gB >= 0){
      const float* lwB = &low[((size_t)gB * B_ + b) * R_];
      #pragma unroll
      for (int r = 0; r < R_; r++){
        float lv = lwB[r];
        u16x4 w = *(const u16x4*)&LB[r*F_ + t*4];
        v.x += lv * b2f(w[0]); v.y += lv * b2f(w[1]);
        v.z += lv * b2f(w[2]); v.w += lv * b2f(w[3]);
      }
    }
    *(float4*)&Y[(size_t)b * F_ + t*4] = v;
  }
}

// ---------------- kernel 6: gates + output ----------------
__device__ __forceinline__ float sigf(float x){ return 1.f / (1.f + __expf(-x)); }
__device__ __forceinline__ float tanh_f(float x){
  float e = __expf(-2.f * fabsf(x));
  float v = (1.f - e) / (1.f + e);
  return copysignf(v, x);
}
__device__ __forceinline__ float gru1(float zr, float zu, float zic, float zrc, float c){
  float r = sigf(zr), u = sigf(zu);
  float cand = tanh_f(zic + r * zrc);
  return (1.f - u) * cand + u * c;
}

__global__ void final_kernel(const float* __restrict__ carry,
                             const float* __restrict__ bias_ir, const float* __restrict__ bias_iu,
                             const float* __restrict__ bias_ic,
                             const float* __restrict__ Y0, const float* __restrict__ Y1,
                             const float* __restrict__ Y2, const float* __restrict__ Y3,
                             float* __restrict__ out){
  int i = blockIdx.x * blockDim.x + threadIdx.x;
  if (i >= B_ * F_ / 4) return;
  int b = i >> 8, j = (i & 255) * 4;
  size_t idx = (size_t)b * F_ + j;
  float4 zr = *(const float4*)&Y0[idx];
  float4 zu = *(const float4*)&Y1[idx];
  float4 zi = *(const float4*)&Y2[idx];
  float4 zc = *(const float4*)&Y3[idx];
  float4 br = *(const float4*)&bias_ir[j];
  float4 bu = *(const float4*)&bias_iu[j];
  float4 bc = *(const float4*)&bias_ic[j];
  float4 cv = *(const float4*)&carry[idx];
  float4 o;
  o.x = gru1(zr.x + br.x, zu.x + bu.x, zi.x + bc.x, zc.x, cv.x);
  o.y = gru1(zr.y + br.y, zu.y + bu.y, zi.y + bc.y, zc.y, cv.y);
  o.z = gru1(zr.z + br.z, zu.z + bu.z, zi.z + bc.z, zc.z, cv.z);
  o.w = gru1(zr.w + br.w, zu.w + bu.w, zi.w + bc.w, zc.w, cv.w);
  *(float4*)&out[idx] = o;
}

extern "C" void kernel_launch(void* const* d_in, const int* in_sizes, int n_in,
                              void* d_out, int out_size, void* d_ws, size_t ws_size,
                              hipStream_t stream){
  const float* carry   = (const float*)d_in[0];
  const float* x       = (const float*)d_in[1];
  const int*   ids     = (const int*)d_in[2];
  const float* w_ir    = (const float*)d_in[3];
  const float* bias_ir = (const float*)d_in[4];
  const float* la_ir   = (const float*)d_in[5];
  const float* lb_ir   = (const float*)d_in[6];
  const float* w_iu    = (const float*)d_in[7];
  const float* bias_iu = (const float*)d_in[8];
  const float* la_iu   = (const float*)d_in[9];
  const float* lb_iu   = (const float*)d_in[10];
  const float* w_ic    = (const float*)d_in[11];
  const float* bias_ic = (const float*)d_in[12];
  const float* la_ic   = (const float*)d_in[13];
  const float* lb_ic   = (const float*)d_in[14];
  const float* w_rr    = (const float*)d_in[15];
  const float* la_rr   = (const float*)d_in[16];
  const float* lb_rr   = (const float*)d_in[17];
  const float* w_ru    = (const float*)d_in[18];
  const float* la_ru   = (const float*)d_in[19];
  const float* lb_ru   = (const float*)d_in[20];
  const float* w_rc    = (const float*)d_in[21];
  const float* la_rc   = (const float*)d_in[22];
  const float* lb_rc   = (const float*)d_in[23];

  char* ws = (char*)d_ws;
  unsigned short* XC  = (unsigned short*)(ws + 0);           // 8 MiB
  unsigned short* W0t = (unsigned short*)(ws + 8388608);     // 4 MiB
  unsigned short* W1t = (unsigned short*)(ws + 12582912);    // 4 MiB
  unsigned short* W2t = (unsigned short*)(ws + 16777216);    // 2 MiB
  unsigned short* W3t = (unsigned short*)(ws + 18874368);    // 2 MiB
  float* Y0  = (float*)(ws + 20971520);                      // 8 MiB each
  float* Y1  = (float*)(ws + 29360128);
  float* Y2  = (float*)(ws + 37748736);
  float* Y3  = (float*)(ws + 46137344);
  float* low = (float*)(ws + 54525952);                      // 768 KiB
  int* starts = (int*)(ws + 55312384);
  int* order  = (int*)(ws + 55313408);

  cast_xc_kernel<<<dim3(2048), dim3(256), 0, stream>>>(x, carry, XC);
  wcast_kernel<<<dim3(256, 6), dim3(256), 0, stream>>>(w_ir, w_iu, w_ic, w_rr, w_ru, w_rc,
                                                       W0t, W1t, W2t, W3t);
  bucket_kernel<<<dim3(1), dim3(256), 0, stream>>>(ids, starts, order);
  low_kernel<<<dim3(64, 6), dim3(256), 0, stream>>>(x, carry, la_ir, la_iu, la_ic,
                                                    la_rr, la_ru, la_rc, starts, order, low);
  gemm_kernel<<<dim3(128, 4), dim3(256), 0, stream>>>(XC, W0t, W1t, W2t, W3t, Y0, Y1, Y2, Y3);
  delta_kernel<<<dim3(64, 4), dim3(256), 0, stream>>>(lb_ir, lb_iu, lb_ic, lb_rr, lb_ru, lb_rc,
                                                      starts, order, low, Y0, Y1, Y2, Y3);
  final_kernel<<<dim3(2048), dim3(256), 0, stream>>>(carry, bias_ir, bias_iu, bias_ic,
                                                     Y0, Y1, Y2, Y3, (float*)d_out);
}

// Round 2
// 118.114 us; speedup vs baseline: 1.7675x; 1.7675x over previous
//
#include <hip/hip_runtime.h>
#include <stdint.h>

#define B_  2048
#define D_  1024
#define F_  1024
#define S_  64
#define R_  16

typedef __attribute__((ext_vector_type(8))) short  s16x8;
typedef __attribute__((ext_vector_type(4))) unsigned short u16x4;
typedef __attribute__((ext_vector_type(8))) unsigned short u16x8;
typedef __attribute__((ext_vector_type(4))) float  f32x4;

__device__ __forceinline__ unsigned short f2b(float f){
  unsigned u = __float_as_uint(f);
  u = u + 0x7fffu + ((u >> 16) & 1u);   // RNE to bf16
  return (unsigned short)(u >> 16);
}
__device__ __forceinline__ float b2f(unsigned short s){
  return __uint_as_float(((unsigned)s) << 16);
}

__device__ __forceinline__ void gload16(const void* g, void* l){
  __builtin_amdgcn_global_load_lds((const __attribute__((address_space(1))) unsigned int*)g,
                                   (__attribute__((address_space(3))) unsigned int*)l, 16, 0, 0);
}

// ---------------- kernel 1a: XC = [bf16(x) | bf16(carry)]  (B x 2048) ----------------
__global__ void cast_xc_kernel(const float* __restrict__ x, const float* __restrict__ carry,
                               unsigned short* __restrict__ XC){
  int i = blockIdx.x * blockDim.x + threadIdx.x;   // one float4 per row-half
  if (i >= B_ * (D_/4)) return;
  int b = i >> 8;
  int j = (i & 255) * 4;
  float4 xv = *(const float4*)&x[(size_t)b*D_ + j];
  float4 cv = *(const float4*)&carry[(size_t)b*F_ + j];
  u16x4 xs, cs;
  xs[0]=f2b(xv.x); xs[1]=f2b(xv.y); xs[2]=f2b(xv.z); xs[3]=f2b(xv.w);
  cs[0]=f2b(cv.x); cs[1]=f2b(cv.y); cs[2]=f2b(cv.z); cs[3]=f2b(cv.w);
  *(u16x4*)&XC[(size_t)b*2048 + j]        = xs;
  *(u16x4*)&XC[(size_t)b*2048 + 1024 + j] = cs;
}

// ---------------- kernel 1b: transpose-cast weights into Wt[n][k] bf16 ----------------
__global__ void wcast_kernel(const float* __restrict__ w_ir, const float* __restrict__ w_iu,
                             const float* __restrict__ w_ic, const float* __restrict__ w_rr,
                             const float* __restrict__ w_ru, const float* __restrict__ w_rc,
                             unsigned short* __restrict__ W0t, unsigned short* __restrict__ W1t,
                             unsigned short* __restrict__ W2t, unsigned short* __restrict__ W3t){
  int g = blockIdx.y;
  const float* W; unsigned short* O; int st, ko;
  switch(g){
    case 0:  W=w_ir; O=W0t; st=2048; ko=0;    break;
    case 1:  W=w_iu; O=W1t; st=2048; ko=0;    break;
    case 2:  W=w_ic; O=W2t; st=1024; ko=0;    break;
    case 3:  W=w_rr; O=W0t; st=2048; ko=1024; break;
    case 4:  W=w_ru; O=W1t; st=2048; ko=1024; break;
    default: W=w_rc; O=W3t; st=1024; ko=0;    break;
  }
  __shared__ unsigned short T[64][72];   // row stride 144B = 9*16B (aligned)
  int t = threadIdx.x;
  int n0 = (blockIdx.x & 15) * 64;
  int k0 = (blockIdx.x >> 4) * 64;
  int c4 = (t & 15) * 4;
  int kk = t >> 4;
  #pragma unroll
  for (int i = 0; i < 4; i++){
    int k = kk + i*16;
    float4 v = *(const float4*)&W[(size_t)(k0+k)*F_ + n0 + c4];
    T[c4+0][k] = f2b(v.x); T[c4+1][k] = f2b(v.y); T[c4+2][k] = f2b(v.z); T[c4+3][k] = f2b(v.w);
  }
  __syncthreads();
  int n = t >> 2, ch = (t & 3) * 16;
  u16x8 a = *(const u16x8*)&T[n][ch];
  u16x8 b = *(const u16x8*)&T[n][ch+8];
  *(u16x8*)&O[(size_t)(n0+n)*st + ko + k0 + ch]     = a;
  *(u16x8*)&O[(size_t)(n0+n)*st + ko + k0 + ch + 8] = b;
}

// ---------------- kernel 2: bucket examples by adapter id ----------------
__global__ void bucket_kernel(const int* __restrict__ ids, int* __restrict__ starts,
                              int* __restrict__ order){
  __shared__ int cnt[S_]; __shared__ int off[S_+1]; __shared__ int cur[S_];
  int t = threadIdx.x;
  if (t < S_) cnt[t] = 0;
  __syncthreads();
  for (int b = t; b < B_; b += 256) atomicAdd(&cnt[ids[b]], 1);
  __syncthreads();
  if (t == 0){ off[0] = 0; for (int s2 = 0; s2 < S_; s2++) off[s2+1] = off[s2] + cnt[s2]; }
  __syncthreads();
  if (t < S_) cur[t] = off[t];
  __syncthreads();
  for (int b = t; b < B_; b += 256){ int p = atomicAdd(&cur[ids[b]], 1); order[p] = b; }
  if (t < S_+1) starts[t] = off[t];
}

// ---------------- kernel 3: low[g][b][r] = XC[b, gslice] . la_g[id[b]][:,r]  (MFMA) ------
// One block per (adapter s, group g). la^T staged in LDS [16][1024+8] bf16.
// Each wave owns m-tiles of 16 bucketed examples, 2 tiles in flight.
__global__ __launch_bounds__(256) void low_kernel(
    const unsigned short* __restrict__ XC,
    const float* __restrict__ la_ir, const float* __restrict__ la_iu,
    const float* __restrict__ la_ic, const float* __restrict__ la_rr,
    const float* __restrict__ la_ru, const float* __restrict__ la_rc,
    const int* __restrict__ starts, const int* __restrict__ order,
    float* __restrict__ low){
  int s = blockIdx.x, g = blockIdx.y;
  const float* la;
  switch(g){ case 0: la=la_ir; break; case 1: la=la_iu; break; case 2: la=la_ic; break;
             case 3: la=la_rr; break; case 4: la=la_ru; break; default: la=la_rc; break; }
  int kofs = (g < 3) ? 0 : 1024;
  la += (size_t)s * D_ * R_;
  __shared__ unsigned short LA[16 * 1032];   // [r][d], stride 1032 (pad 8) ~ 33 KB
  int t = threadIdx.x;
  for (int i4 = t; i4 < D_*R_/4; i4 += 256){
    float4 v = *(const float4*)&la[i4*4];
    int d = i4 >> 2, r0 = (i4 & 3) * 4;
    LA[(r0+0)*1032 + d] = f2b(v.x);
    LA[(r0+1)*1032 + d] = f2b(v.y);
    LA[(r0+2)*1032 + d] = f2b(v.z);
    LA[(r0+3)*1032 + d] = f2b(v.w);
  }
  __syncthreads();
  int start = starts[s], cnt = starts[s+1] - start;
  if (cnt == 0) return;
  int lane = t & 63, wave = t >> 6;
  int l15 = lane & 15, kq = (lane >> 4) * 8;
  int ntiles = (cnt + 15) >> 4;
  for (int mt = wave*2; mt < ntiles; mt += 8){
    bool two = (mt + 1 < ntiles);
    int m0 = mt*16 + l15;       if (m0 >= cnt) m0 = cnt - 1;
    int m1 = (mt+1)*16 + l15;   if (m1 >= cnt) m1 = cnt - 1;
    int e0 = order[start + m0];
    int e1 = two ? order[start + m1] : e0;
    const unsigned short* A0 = XC + (size_t)e0*2048 + kofs + kq;
    const unsigned short* A1 = XC + (size_t)e1*2048 + kofs + kq;
    const unsigned short* Bp = &LA[l15*1032 + kq];
    f32x4 acc0 = {}, acc1 = {};
    #pragma unroll 4
    for (int kt = 0; kt < 1024; kt += 32){
      s16x8 a0 = *(const s16x8*)(A0 + kt);
      s16x8 a1 = *(const s16x8*)(A1 + kt);
      s16x8 b  = *(const s16x8*)(Bp + kt);
      acc0 = __builtin_amdgcn_mfma_f32_16x16x32_bf16(a0, b, acc0, 0, 0, 0);
      acc1 = __builtin_amdgcn_mfma_f32_16x16x32_bf16(a1, b, acc1, 0, 0, 0);
    }
    int rowb = (lane >> 4) * 4;
    #pragma unroll
    for (int i = 0; i < 4; i++){
      int m = mt*16 + rowb + i;
      if (m < cnt){
        int e = order[start + m];
        low[((size_t)g*B_ + e)*R_ + l15] = acc0[i];
      }
    }
    if (two){
      #pragma unroll
      for (int i = 0; i < 4; i++){
        int m = (mt+1)*16 + rowb + i;
        if (m < cnt){
          int e = order[start + m];
          low[((size_t)g*B_ + e)*R_ + l15] = acc1[i];
        }
      }
    }
  }
}

// ---------------- kernel 4: MFMA GEMM: Yz = A(XC slice) @ Wzt^T ----------------
__global__ __launch_bounds__(256, 2) void gemm_kernel(
    const unsigned short* __restrict__ XC,
    const unsigned short* __restrict__ W0t, const unsigned short* __restrict__ W1t,
    const unsigned short* __restrict__ W2t, const unsigned short* __restrict__ W3t,
    float* __restrict__ Y0, float* __restrict__ Y1,
    float* __restrict__ Y2, float* __restrict__ Y3){
  int z = blockIdx.y;
  const unsigned short* Wt; float* Y; int K, kofs;
  if (z == 0){ Wt = W0t; Y = Y0; K = 2048; kofs = 0; }
  else if (z == 1){ Wt = W1t; Y = Y1; K = 2048; kofs = 0; }
  else if (z == 2){ Wt = W2t; Y = Y2; K = 1024; kofs = 0; }
  else { Wt = W3t; Y = Y3; K = 1024; kofs = 1024; }

  __shared__ unsigned short As[128*32];  // [128 rows][32 k] bf16
  __shared__ unsigned short Ws[128*32];  // [128 cols][32 k] bf16

  int t = threadIdx.x;
  int lane = t & 63, wave = t >> 6;
  int mt = blockIdx.x >> 3, nt = blockIdx.x & 7;
  int row0 = mt * 128, col0 = nt * 128;
  int wrow = (wave >> 1) * 64, wcol = (wave & 1) * 64;

  int arow = t >> 2;          // 0..63
  int achk = (t & 3) * 8;     // k element offset (8 bf16 = 16B)

  f32x4 acc[4][4] = {};

  const unsigned short* Abase  = XC + (size_t)(row0 + arow) * 2048 + kofs + achk;
  const unsigned short* A2base = Abase + (size_t)64 * 2048;
  const unsigned short* Wbase  = Wt + (size_t)(col0 + arow) * K + achk;
  const unsigned short* W2base = Wbase + (size_t)64 * K;

  int l15 = lane & 15, kof = (lane >> 4) * 8;

  for (int kt = 0; kt < K; kt += 32){
    gload16(Abase  + kt, &As[t*8]);
    gload16(A2base + kt, &As[2048 + t*8]);
    gload16(Wbase  + kt, &Ws[t*8]);
    gload16(W2base + kt, &Ws[2048 + t*8]);
    __syncthreads();
    s16x8 af[4], bfr[4];
    #pragma unroll
    for (int m = 0; m < 4; m++)
      af[m] = *(const s16x8*)&As[(wrow + m*16 + l15)*32 + kof];
    #pragma unroll
    for (int n = 0; n < 4; n++)
      bfr[n] = *(const s16x8*)&Ws[(wcol + n*16 + l15)*32 + kof];
    #pragma unroll
    for (int m = 0; m < 4; m++){
      #pragma unroll
      for (int n = 0; n < 4; n++){
        acc[m][n] = __builtin_amdgcn_mfma_f32_16x16x32_bf16(af[m], bfr[n], acc[m][n], 0, 0, 0);
      }
    }
    __syncthreads();
  }

  int orow = row0 + wrow + (lane >> 4) * 4;
  int ocol = col0 + wcol + l15;
  #pragma unroll
  for (int m = 0; m < 4; m++){
    #pragma unroll
    for (int n = 0; n < 4; n++){
      #pragma unroll
      for (int i = 0; i < 4; i++){
        Y[(size_t)(orow + m*16 + i) * F_ + ocol + n*16] = acc[m][n][i];
      }
    }
  }
}

// ---------------- kernel 5: Yz += low_gA @ lb_gA[id]  (+ low_gB @ lb_gB[id]) ----------------
// 1024 threads: 4 example-lanes x 256 column-threads.
__global__ __launch_bounds__(1024) void delta_kernel(
                             const float* __restrict__ lb_ir, const float* __restrict__ lb_iu,
                             const float* __restrict__ lb_ic, const float* __restrict__ lb_rr,
                             const float* __restrict__ lb_ru, const float* __restrict__ lb_rc,
                             const int* __restrict__ starts, const int* __restrict__ order,
                             const float* __restrict__ low,
                             float* __restrict__ Y0, float* __restrict__ Y1,
                             float* __restrict__ Y2, float* __restrict__ Y3){
  int s = blockIdx.x, z = blockIdx.y;
  const float* lbs[6] = {lb_ir, lb_iu, lb_ic, lb_rr, lb_ru, lb_rc};
  int gA, gB; float* Y;
  if (z == 0){ gA = 0; gB = 3; Y = Y0; }
  else if (z == 1){ gA = 1; gB = 4; Y = Y1; }
  else if (z == 2){ gA = 2; gB = -1; Y = Y2; }
  else { gA = 5; gB = -1; Y = Y3; }

  __shared__ unsigned short LA[R_*F_];   // 32 KB
  __shared__ unsigned short LB[R_*F_];   // 32 KB
  int t = threadIdx.x;
  const float* lbA = lbs[gA] + (size_t)s * R_ * F_;
  for (int i4 = t; i4 < R_*F_/4; i4 += 1024){
    float4 v = *(const float4*)&lbA[i4*4];
    u16x4 o; o[0]=f2b(v.x); o[1]=f2b(v.y); o[2]=f2b(v.z); o[3]=f2b(v.w);
    *(u16x4*)&LA[i4*4] = o;
  }
  if (gB >= 0){
    const float* lbB = lbs[gB] + (size_t)s * R_ * F_;
    for (int i4 = t; i4 < R_*F_/4; i4 += 1024){
      float4 v = *(const float4*)&lbB[i4*4];
      u16x4 o; o[0]=f2b(v.x); o[1]=f2b(v.y); o[2]=f2b(v.z); o[3]=f2b(v.w);
      *(u16x4*)&LB[i4*4] = o;
    }
  }
  __syncthreads();
  int start = starts[s], cnt = starts[s+1] - start;
  int ct = t & 255, ml = t >> 8;
  for (int m = ml; m < cnt; m += 4){
    int b = order[start + m];
    float4 v = *(float4*)&Y[(size_t)b * F_ + ct*4];
    const float* lwA = &low[((size_t)gA * B_ + b) * R_];
    #pragma unroll
    for (int r = 0; r < R_; r++){
      float lv = lwA[r];
      u16x4 w = *(const u16x4*)&LA[r*F_ + ct*4];
      v.x += lv * b2f(w[0]); v.y += lv * b2f(w[1]);
      v.z += lv * b2f(w[2]); v.w += lv * b2f(w[3]);
    }
    if (gB >= 0){
      const float* lwB = &low[((size_t)gB * B_ + b) * R_];
      #pragma unroll
      for (int r = 0; r < R_; r++){
        float lv = lwB[r];
        u16x4 w = *(const u16x4*)&LB[r*F_ + ct*4];
        v.x += lv * b2f(w[0]); v.y += lv * b2f(w[1]);
        v.z += lv * b2f(w[2]); v.w += lv * b2f(w[3]);
      }
    }
    *(float4*)&Y[(size_t)b * F_ + ct*4] = v;
  }
}

// ---------------- kernel 6: gates + output ----------------
__device__ __forceinline__ float sigf(float x){ return 1.f / (1.f + __expf(-x)); }
__device__ __forceinline__ float tanh_f(float x){
  float e = __expf(-2.f * fabsf(x));
  float v = (1.f - e) / (1.f + e);
  return copysignf(v, x);
}
__device__ __forceinline__ float gru1(float zr, float zu, float zic, float zrc, float c){
  float r = sigf(zr), u = sigf(zu);
  float cand = tanh_f(zic + r * zrc);
  return (1.f - u) * cand + u * c;
}

__global__ void final_kernel(const float* __restrict__ carry,
                             const float* __restrict__ bias_ir, const float* __restrict__ bias_iu,
                             const float* __restrict__ bias_ic,
                             const float* __restrict__ Y0, const float* __restrict__ Y1,
                             const float* __restrict__ Y2, const float* __restrict__ Y3,
                             float* __restrict__ out){
  int i = blockIdx.x * blockDim.x + threadIdx.x;
  if (i >= B_ * F_ / 4) return;
  int b = i >> 8, j = (i & 255) * 4;
  size_t idx = (size_t)b * F_ + j;
  float4 zr = *(const float4*)&Y0[idx];
  float4 zu = *(const float4*)&Y1[idx];
  float4 zi = *(const float4*)&Y2[idx];
  float4 zc = *(const float4*)&Y3[idx];
  float4 br = *(const float4*)&bias_ir[j];
  float4 bu = *(const float4*)&bias_iu[j];
  float4 bc = *(const float4*)&bias_ic[j];
  float4 cv = *(const float4*)&carry[idx];
  float4 o;
  o.x = gru1(zr.x + br.x, zu.x + bu.x, zi.x + bc.x, zc.x, cv.x);
  o.y = gru1(zr.y + br.y, zu.y + bu.y, zi.y + bc.y, zc.y, cv.y);
  o.z = gru1(zr.z + br.z, zu.z + bu.z, zi.z + bc.z, zc.z, cv.z);
  o.w = gru1(zr.w + br.w, zu.w + bu.w, zi.w + bc.w, zc.w, cv.w);
  *(float4*)&out[idx] = o;
}

extern "C" void kernel_launch(void* const* d_in, const int* in_sizes, int n_in,
                              void* d_out, int out_size, void* d_ws, size_t ws_size,
                              hipStream_t stream){
  const float* carry   = (const float*)d_in[0];
  const float* x       = (const float*)d_in[1];
  const int*   ids     = (const int*)d_in[2];
  const float* w_ir    = (const float*)d_in[3];
  const float* bias_ir = (const float*)d_in[4];
  const float* la_ir   = (const float*)d_in[5];
  const float* lb_ir   = (const float*)d_in[6];
  const float* w_iu    = (const float*)d_in[7];
  const float* bias_iu = (const float*)d_in[8];
  const float* la_iu   = (const float*)d_in[9];
  const float* lb_iu   = (const float*)d_in[10];
  const float* w_ic    = (const float*)d_in[11];
  const float* bias_ic = (const float*)d_in[12];
  const float* la_ic   = (const float*)d_in[13];
  const float* lb_ic   = (const float*)d_in[14];
  const float* w_rr    = (const float*)d_in[15];
  const float* la_rr   = (const float*)d_in[16];
  const float* lb_rr   = (const float*)d_in[17];
  const float* w_ru    = (const float*)d_in[18];
  const float* la_ru   = (const float*)d_in[19];
  const float* lb_ru   = (const float*)d_in[20];
  const float* w_rc    = (const float*)d_in[21];
  const float* la_rc   = (const float*)d_in[22];
  const float* lb_rc   = (const float*)d_in[23];

  char* ws = (char*)d_ws;
  unsigned short* XC  = (unsigned short*)(ws + 0);           // 8 MiB
  unsigned short* W0t = (unsigned short*)(ws + 8388608);     // 4 MiB
  unsigned short* W1t = (unsigned short*)(ws + 12582912);    // 4 MiB
  unsigned short* W2t = (unsigned short*)(ws + 16777216);    // 2 MiB
  unsigned short* W3t = (unsigned short*)(ws + 18874368);    // 2 MiB
  float* Y0  = (float*)(ws + 20971520);                      // 8 MiB each
  float* Y1  = (float*)(ws + 29360128);
  float* Y2  = (float*)(ws + 37748736);
  float* Y3  = (float*)(ws + 46137344);
  float* low = (float*)(ws + 54525952);                      // 768 KiB
  int* starts = (int*)(ws + 55312384);
  int* order  = (int*)(ws + 55313408);

  cast_xc_kernel<<<dim3(2048), dim3(256), 0, stream>>>(x, carry, XC);
  wcast_kernel<<<dim3(256, 6), dim3(256), 0, stream>>>(w_ir, w_iu, w_ic, w_rr, w_ru, w_rc,
                                                       W0t, W1t, W2t, W3t);
  bucket_kernel<<<dim3(1), dim3(256), 0, stream>>>(ids, starts, order);
  low_kernel<<<dim3(64, 6), dim3(256), 0, stream>>>(XC, la_ir, la_iu, la_ic,
                                                    la_rr, la_ru, la_rc, starts, order, low);
  gemm_kernel<<<dim3(128, 4), dim3(256), 0, stream>>>(XC, W0t, W1t, W2t, W3t, Y0, Y1, Y2, Y3);
  delta_kernel<<<dim3(64, 4), dim3(1024), 0, stream>>>(lb_ir, lb_iu, lb_ic, lb_rr, lb_ru, lb_rc,
                                                       starts, order, low, Y0, Y1, Y2, Y3);
  final_kernel<<<dim3(2048), dim3(256), 0, stream>>>(carry, bias_ir, bias_iu, bias_ic,
                                                     Y0, Y1, Y2, Y3, (float*)d_out);
}